// Round 9
// baseline (50.504 us; speedup 1.0000x reference)
//
#include <hip/hip_runtime.h>
#include <math.h>
#include <string.h>

#define KC 32

typedef __attribute__((ext_vector_type(8))) short bf16x8;
typedef __attribute__((ext_vector_type(4))) float f32x4;

__device__ __forceinline__ unsigned pack2_bf16(float a, float b) {
    unsigned ua = __float_as_uint(a); ua += 0x7fffu + ((ua >> 16) & 1u);
    unsigned ub = __float_as_uint(b); ub += 0x7fffu + ((ub >> 16) & 1u);
    return (ua >> 16) | (ub & 0xffff0000u);
}

// 16-KB table of pre-packed MFMA basis fragments, computed ONCE on host at
// .so load (fp64-exact, RTN to bf16) and hipMemcpyAsync'd to d_ws per call:
//   frag[(c*2+sub)*64 + lane], elem i = bf16(2*cos(pi*(2*A+1)*B/512)),
//   A = 32c + 8*(lane>>4) + i, B = sub*16 + (lane&15).
// Serves stage 1 (A=w, B=l: Cw B-operand) AND stage 2 (A=h, B=k: Ch A-operand).
static unsigned short h_tab[8192];
static const bool h_tab_ready = []() {
    for (int t = 0; t < 1024; ++t) {
        int c = t >> 7, sub = (t >> 6) & 1, lane = t & 63;
        int g = lane >> 4, cl = lane & 15;
        for (int i = 0; i < 8; ++i) {
            int A = 32 * c + 8 * g + i;
            int B = sub * 16 + cl;
            double v = 2.0 * cos(M_PI * (double)(2 * A + 1) * (double)B / 512.0);
            float f = (float)v;
            unsigned u;
            memcpy(&u, &f, 4);
            u += 0x7fffu + ((u >> 16) & 1u);
            h_tab[t * 8 + i] = (unsigned short)(u >> 16);
        }
    }
    return true;
}();

// Block = 256 thr = 4 waves = 1 image.
// Stage 1: U[256 h][32 l] = X @ Cw^T. K = w (8 chunks of 32). X-chunk staged
//   fp32->bf16 into a 2x20KB LDS ring, row-major [256 h][32 w] padded to 80 B/row
//   (pad => both ds_write_b64 staging and ds_read_b128 A-frags hit the dense
//   8-access/bank floor; no swizzle). A-frag = 8 contiguous w per lane;
//   B-frag = table. Wave wv owns m-tiles {wv,wv+4,wv+8,wv+12}, both n-tiles.
// U^T [32 l][256 h] bf16, 528 B/row, aliased onto ring buf0.
// Stage 2: out[32 k][32 l] = Ch @ U. A-frag = table, B-frag = ds_read_b128 from
//   U^T (contiguous h). Wave = (mt2 = wv>>1, nt2 = wv&1), 8 MFMAs, direct global out.
__global__ __launch_bounds__(256, 4) void dct_trunc_kernel(
    const float* __restrict__ x, float* __restrict__ out,
    const unsigned short* __restrict__ tab) {
    __shared__ uint4 ldsbuf[2560];                  // 40 KB
    char* lds = (char*)ldsbuf;
    const bf16x8* __restrict__ tabv = (const bf16x8*)tab;

    const int tid  = threadIdx.x;
    const int lane = tid & 63;
    const int wv   = tid >> 6;
    const int g    = lane >> 4;
    const int cl   = lane & 15;
    const int img  = blockIdx.x;
    const float* __restrict__ xi = x + (size_t)img * 65536;

    // staging assignment: thread covers rows {srow, srow+32, ..., srow+224},
    // w-segment sc*4..sc*4+3 of the 32-w chunk (8 lanes x float4 = 128 B/row).
    const int srow = tid >> 3;      // 0..31
    const int sc   = tid & 7;       // 0..7

    float4 pf0, pf1, pf2, pf3, pf4, pf5, pf6, pf7;

#define STAGE_LOAD(c_) do { \
    const float* s_ = xi + (size_t)(c_) * 32 + (size_t)srow * 256 + sc * 4; \
    pf0 = *(const float4*)(s_ + 0 * 8192); \
    pf1 = *(const float4*)(s_ + 1 * 8192); \
    pf2 = *(const float4*)(s_ + 2 * 8192); \
    pf3 = *(const float4*)(s_ + 3 * 8192); \
    pf4 = *(const float4*)(s_ + 4 * 8192); \
    pf5 = *(const float4*)(s_ + 5 * 8192); \
    pf6 = *(const float4*)(s_ + 6 * 8192); \
    pf7 = *(const float4*)(s_ + 7 * 8192); \
} while (0)

#define STAGE_WRITE(base_) do { \
    char* b_ = lds + (base_) + srow * 80 + sc * 8; \
    *(uint2*)(b_ + 0 * 2560) = make_uint2(pack2_bf16(pf0.x, pf0.y), pack2_bf16(pf0.z, pf0.w)); \
    *(uint2*)(b_ + 1 * 2560) = make_uint2(pack2_bf16(pf1.x, pf1.y), pack2_bf16(pf1.z, pf1.w)); \
    *(uint2*)(b_ + 2 * 2560) = make_uint2(pack2_bf16(pf2.x, pf2.y), pack2_bf16(pf2.z, pf2.w)); \
    *(uint2*)(b_ + 3 * 2560) = make_uint2(pack2_bf16(pf3.x, pf3.y), pack2_bf16(pf3.z, pf3.w)); \
    *(uint2*)(b_ + 4 * 2560) = make_uint2(pack2_bf16(pf4.x, pf4.y), pack2_bf16(pf4.z, pf4.w)); \
    *(uint2*)(b_ + 5 * 2560) = make_uint2(pack2_bf16(pf5.x, pf5.y), pack2_bf16(pf5.z, pf5.w)); \
    *(uint2*)(b_ + 6 * 2560) = make_uint2(pack2_bf16(pf6.x, pf6.y), pack2_bf16(pf6.z, pf6.w)); \
    *(uint2*)(b_ + 7 * 2560) = make_uint2(pack2_bf16(pf7.x, pf7.y), pack2_bf16(pf7.z, pf7.w)); \
} while (0)

    f32x4 a00 = {0.f,0.f,0.f,0.f}, a01 = a00, a10 = a00, a11 = a00;
    f32x4 a20 = a00, a21 = a00, a30 = a00, a31 = a00;

    // Prologue: chunk 0 -> buf 0
    STAGE_LOAD(0);
    STAGE_WRITE(0);

    const int frow = cl * 80 + g * 16;   // A-frag byte offset within a 16-row tile

    #pragma unroll 2
    for (int c = 0; c < 8; ++c) {
        __syncthreads();                 // chunk c resident; buf (c+1)&1 free

        bf16x8 bf0 = tabv[(c * 2 + 0) * 64 + lane];   // Cw frags (L1/L2-hot)
        bf16x8 bf1 = tabv[(c * 2 + 1) * 64 + lane];
        if (c < 7) STAGE_LOAD(c + 1);    // issue early; lands under MFMAs

        const char* xb = lds + (c & 1) * 20480;
        bf16x8 xf0 = *(const bf16x8*)(xb + (wv +  0) * 1280 + frow);
        bf16x8 xf1 = *(const bf16x8*)(xb + (wv +  4) * 1280 + frow);
        bf16x8 xf2 = *(const bf16x8*)(xb + (wv +  8) * 1280 + frow);
        bf16x8 xf3 = *(const bf16x8*)(xb + (wv + 12) * 1280 + frow);

        a00 = __builtin_amdgcn_mfma_f32_16x16x32_bf16(xf0, bf0, a00, 0, 0, 0);
        a01 = __builtin_amdgcn_mfma_f32_16x16x32_bf16(xf0, bf1, a01, 0, 0, 0);
        a10 = __builtin_amdgcn_mfma_f32_16x16x32_bf16(xf1, bf0, a10, 0, 0, 0);
        a11 = __builtin_amdgcn_mfma_f32_16x16x32_bf16(xf1, bf1, a11, 0, 0, 0);
        a20 = __builtin_amdgcn_mfma_f32_16x16x32_bf16(xf2, bf0, a20, 0, 0, 0);
        a21 = __builtin_amdgcn_mfma_f32_16x16x32_bf16(xf2, bf1, a21, 0, 0, 0);
        a30 = __builtin_amdgcn_mfma_f32_16x16x32_bf16(xf3, bf0, a30, 0, 0, 0);
        a31 = __builtin_amdgcn_mfma_f32_16x16x32_bf16(xf3, bf1, a31, 0, 0, 0);

        if (c < 7) STAGE_WRITE(((c + 1) & 1) * 20480);
    }

    // ---- U^T write: [32 l][256 h] bf16, 528 B rows, aliased on buf0.
    // buf0's last reads were chunk 6, fenced by the barrier at top of c=7.
    // C/D layout: col = cl (= l within n-tile), row = 4g + r (= h within m-tile).
#define UTW(q_, A0_, A1_) do { \
    char* u0 = lds + (0 * 16 + cl) * 528 + (wv + 4 * (q_)) * 32 + g * 8; \
    char* u1 = lds + (1 * 16 + cl) * 528 + (wv + 4 * (q_)) * 32 + g * 8; \
    *(uint2*)u0 = make_uint2(pack2_bf16(A0_[0], A0_[1]), pack2_bf16(A0_[2], A0_[3])); \
    *(uint2*)u1 = make_uint2(pack2_bf16(A1_[0], A1_[1]), pack2_bf16(A1_[2], A1_[3])); \
} while (0)
    UTW(0, a00, a01);
    UTW(1, a10, a11);
    UTW(2, a20, a21);
    UTW(3, a30, a31);
    __syncthreads();

    // ---- Stage 2: out = Ch @ U (K = h, 8 chunks) ----
    const int mt2 = wv >> 1;
    const int nt2 = wv & 1;
    f32x4 acc2 = {0.f, 0.f, 0.f, 0.f};
    const char* ub = lds + (nt2 * 16 + cl) * 528 + g * 16;
    #pragma unroll
    for (int c2 = 0; c2 < 8; ++c2) {
        bf16x8 af = tabv[(c2 * 2 + mt2) * 64 + lane];           // Ch frag
        bf16x8 uf = *(const bf16x8*)(ub + c2 * 64);             // U^T, contiguous h
        acc2 = __builtin_amdgcn_mfma_f32_16x16x32_bf16(af, uf, acc2, 0, 0, 0);
    }

    float* op = out + (size_t)img * 1024 + (mt2 * 16 + g * 4) * 32 + nt2 * 16 + cl;
    op[0]  = acc2[0];
    op[32] = acc2[1];
    op[64] = acc2[2];
    op[96] = acc2[3];
}

extern "C" void kernel_launch(void* const* d_in, const int* in_sizes, int n_in,
                              void* d_out, int out_size, void* d_ws, size_t ws_size,
                              hipStream_t stream) {
    const float* x = (const float*)d_in[0];
    float* out = (float*)d_out;
    unsigned short* tab = (unsigned short*)d_ws;    // 16 KB fragment table

    (void)h_tab_ready;
    hipMemcpyAsync(tab, h_tab, sizeof(h_tab), hipMemcpyHostToDevice, stream);

    const int n_imgs = in_sizes[0] / 65536;         // 1024
    dct_trunc_kernel<<<n_imgs, 256, 0, stream>>>(x, out, tab);
}